// Round 1
// baseline (927.923 us; speedup 1.0000x reference)
//
#include <hip/hip_runtime.h>
#include <math.h>

#define D 128

// ---------------------------------------------------------------------------
// Collapsed linear GCN:
//   reference never applies ReLU -> whole stack is linear. Only mean_n(h3)
//   reaches the output, so propagate the readout weight vector u backwards:
//     u0 = 1/N,  u_{k+1}[s] = sum_{e: src_e=s} inv_deg[dst_e] * u_k[dst_e]
//   mean(h3) = (((u3^T feat) W0 + s2 b0) W1 + s1 b1) W2 + b2,
//   s_k = sum(u_k).  Then readout/match MLP on 128-vectors.
// ---------------------------------------------------------------------------

// ws layout (floats), per graph block of 4N: [deg/inv, u1, u2, u3]
//   [0,4N)   graph p
//   [4N,8N)  graph s
//   [8N, 8N+128)   r_p
//   [8N+128,+256)  r_s
//   [8N+256,+260)  sums: s1_p, s2_p, s1_s, s2_s

__global__ void deg_kernel(const int* __restrict__ dst_p, const int* __restrict__ dst_s,
                           float* __restrict__ deg_p, float* __restrict__ deg_s, int E) {
    int i = blockIdx.x * blockDim.x + threadIdx.x;
    if (i < E) {
        atomicAdd(&deg_p[dst_p[i]], 1.0f);
    } else {
        i -= E;
        if (i < E) atomicAdd(&deg_s[dst_s[i]], 1.0f);
    }
}

__global__ void inv_kernel(float* __restrict__ deg_p, float* __restrict__ deg_s, int N) {
    int i = blockIdx.x * blockDim.x + threadIdx.x;
    if (i < N) {
        deg_p[i] = 1.0f / fmaxf(deg_p[i], 1.0f);
    } else {
        i -= N;
        if (i < N) deg_s[i] = 1.0f / fmaxf(deg_s[i], 1.0f);
    }
}

// transpose-propagation: u_out[src] += inv_deg[dst] * u_in[dst]
__global__ void prop_kernel(const int* __restrict__ src_p, const int* __restrict__ dst_p,
                            const int* __restrict__ src_s, const int* __restrict__ dst_s,
                            const float* __restrict__ inv_p, const float* __restrict__ inv_s,
                            const float* __restrict__ uin_p, const float* __restrict__ uin_s,
                            float* __restrict__ uout_p, float* __restrict__ uout_s,
                            int E, int first, float u0) {
    int i = blockIdx.x * blockDim.x + threadIdx.x;
    if (i < E) {
        int d = dst_p[i];
        float w = first ? u0 : uin_p[d];
        atomicAdd(&uout_p[src_p[i]], w * inv_p[d]);
    } else {
        i -= E;
        if (i < E) {
            int d = dst_s[i];
            float w = first ? u0 : uin_s[d];
            atomicAdd(&uout_s[src_s[i]], w * inv_s[d]);
        }
    }
}

// r[c] = sum_n u3[n]*feat[n][c]; also s1=sum(u1), s2=sum(u2) (last block per graph)
__global__ void featsum_kernel(const float* __restrict__ feat_p, const float* __restrict__ feat_s,
                               const float* __restrict__ wsp, const float* __restrict__ wss,
                               float* __restrict__ r_p, float* __restrict__ r_s,
                               float* __restrict__ sums, int N) {
    const int g = blockIdx.y;
    const float* feat = g ? feat_s : feat_p;
    const float* base = g ? wss : wsp;
    const float* u1 = base + (size_t)N;
    const float* u2 = base + 2 * (size_t)N;
    const float* u3 = base + 3 * (size_t)N;

    const int nb = gridDim.x - 1;
    if ((int)blockIdx.x == nb) {
        // sum u1, u2
        float a1 = 0.f, a2 = 0.f;
        for (int n = threadIdx.x; n < N; n += blockDim.x) { a1 += u1[n]; a2 += u2[n]; }
        __shared__ float sm1[256], sm2[256];
        sm1[threadIdx.x] = a1; sm2[threadIdx.x] = a2;
        __syncthreads();
        for (int s = 128; s > 0; s >>= 1) {
            if ((int)threadIdx.x < s) { sm1[threadIdx.x] += sm1[threadIdx.x + s]; sm2[threadIdx.x] += sm2[threadIdx.x + s]; }
            __syncthreads();
        }
        if (threadIdx.x == 0) { sums[g * 2 + 0] = sm1[0]; sums[g * 2 + 1] = sm2[0]; }
        return;
    }

    const int col4 = threadIdx.x & 31;  // float4 column (32 * 4 = 128 cols)
    const int rgrp = threadIdx.x >> 5;  // 8 row groups
    const int rows_per_block = (N + nb - 1) / nb;
    const int r0 = blockIdx.x * rows_per_block;
    const int r1 = min(r0 + rows_per_block, N);

    const float4* f4 = (const float4*)feat;
    float4 acc = make_float4(0.f, 0.f, 0.f, 0.f);
    for (int n = r0 + rgrp; n < r1; n += 8) {
        float w = u3[n];
        float4 v = f4[(size_t)n * 32 + col4];
        acc.x += w * v.x; acc.y += w * v.y; acc.z += w * v.z; acc.w += w * v.w;
    }
    __shared__ float4 smem[256];
    smem[threadIdx.x] = acc;
    __syncthreads();
    if (rgrp == 0) {
        float4 t = smem[col4];
        for (int k = 1; k < 8; k++) {
            float4 o = smem[k * 32 + col4];
            t.x += o.x; t.y += o.y; t.z += o.z; t.w += o.w;
        }
        float* r = g ? r_s : r_p;
        atomicAdd(&r[col4 * 4 + 0], t.x);
        atomicAdd(&r[col4 * 4 + 1], t.y);
        atomicAdd(&r[col4 * 4 + 2], t.z);
        atomicAdd(&r[col4 * 4 + 3], t.w);
    }
}

// single block, 128 threads: dense chain + readout + match
__global__ void final_kernel(const float* __restrict__ r_base, const float* __restrict__ sums,
                             const float* __restrict__ W0, const float* __restrict__ b0,
                             const float* __restrict__ W1, const float* __restrict__ b1,
                             const float* __restrict__ W2, const float* __restrict__ b2,
                             const float* __restrict__ Wr, const float* __restrict__ br,
                             const float* __restrict__ Wm1, const float* __restrict__ bm1,
                             const float* __restrict__ Wm2, const float* __restrict__ bm2,
                             float* __restrict__ out) {
    __shared__ float t[128];
    __shared__ float c[256];
    const int j = threadIdx.x;  // 0..127

    for (int g = 0; g < 2; ++g) {
        const float s1 = sums[g * 2 + 0];
        const float s2 = sums[g * 2 + 1];
        t[j] = r_base[g * 128 + j];
        __syncthreads();
        float v = s2 * b0[j];
        for (int i = 0; i < 128; ++i) v += t[i] * W0[i * 128 + j];
        __syncthreads(); t[j] = v; __syncthreads();
        v = s1 * b1[j];
        for (int i = 0; i < 128; ++i) v += t[i] * W1[i * 128 + j];
        __syncthreads(); t[j] = v; __syncthreads();
        v = b2[j];
        for (int i = 0; i < 128; ++i) v += t[i] * W2[i * 128 + j];
        __syncthreads(); t[j] = v; __syncthreads();
        v = br[j];
        for (int i = 0; i < 128; ++i) v += t[i] * Wr[i * 128 + j];
        c[g * 128 + j] = 1.0f / (1.0f + expf(-v));
        __syncthreads();
    }

    float v = bm1[j];
    for (int i = 0; i < 256; ++i) v += c[i] * Wm1[i * 128 + j];
    t[j] = v * Wm2[j];
    __syncthreads();
    if (j == 0) {
        float d = bm2[0];
        for (int i = 0; i < 128; ++i) d += t[i];
        out[0] = 1.0f / (1.0f + expf(-d));
    }
}

extern "C" void kernel_launch(void* const* d_in, const int* in_sizes, int n_in,
                              void* d_out, int out_size, void* d_ws, size_t ws_size,
                              hipStream_t stream) {
    const float* feat_p = (const float*)d_in[0];
    const int*   src_p  = (const int*)d_in[1];
    const int*   dst_p  = (const int*)d_in[2];
    const float* feat_s = (const float*)d_in[3];
    const int*   src_s  = (const int*)d_in[4];
    const int*   dst_s  = (const int*)d_in[5];
    const float* W0 = (const float*)d_in[6];
    const float* b0 = (const float*)d_in[7];
    const float* W1 = (const float*)d_in[8];
    const float* b1 = (const float*)d_in[9];
    const float* W2 = (const float*)d_in[10];
    const float* b2 = (const float*)d_in[11];
    const float* Wr = (const float*)d_in[12];
    const float* br = (const float*)d_in[13];
    const float* Wm1 = (const float*)d_in[14];
    const float* bm1 = (const float*)d_in[15];
    const float* Wm2 = (const float*)d_in[16];
    const float* bm2 = (const float*)d_in[17];
    float* out = (float*)d_out;

    const int N = in_sizes[0] / D;   // 50000
    const int E = in_sizes[1];       // 1600000

    float* ws = (float*)d_ws;
    float* wsp = ws;                       // [deg/inv, u1, u2, u3] for p
    float* wss = ws + 4 * (size_t)N;       // same for s
    float* r_p  = ws + 8 * (size_t)N;
    float* r_s  = r_p + 128;
    float* sums = r_p + 256;

    // zero deg/u arrays + r + sums (ws is poisoned 0xAA each launch)
    hipMemsetAsync(d_ws, 0, (8 * (size_t)N + 256 + 8) * sizeof(float), stream);

    const int BT = 256;
    const int gE2 = (2 * E + BT - 1) / BT;
    const int gN2 = (2 * N + BT - 1) / BT;

    deg_kernel<<<gE2, BT, 0, stream>>>(dst_p, dst_s, wsp, wss, E);
    inv_kernel<<<gN2, BT, 0, stream>>>(wsp, wss, N);

    const float u0 = 1.0f / (float)N;
    prop_kernel<<<gE2, BT, 0, stream>>>(src_p, dst_p, src_s, dst_s, wsp, wss,
                                        nullptr, nullptr, wsp + N, wss + N, E, 1, u0);
    prop_kernel<<<gE2, BT, 0, stream>>>(src_p, dst_p, src_s, dst_s, wsp, wss,
                                        wsp + N, wss + N, wsp + 2 * (size_t)N, wss + 2 * (size_t)N, E, 0, u0);
    prop_kernel<<<gE2, BT, 0, stream>>>(src_p, dst_p, src_s, dst_s, wsp, wss,
                                        wsp + 2 * (size_t)N, wss + 2 * (size_t)N,
                                        wsp + 3 * (size_t)N, wss + 3 * (size_t)N, E, 0, u0);

    featsum_kernel<<<dim3(129, 2), BT, 0, stream>>>(feat_p, feat_s, wsp, wss, r_p, r_s, sums, N);

    final_kernel<<<1, 128, 0, stream>>>(r_p, sums, W0, b0, W1, b1, W2, b2,
                                        Wr, br, Wm1, bm1, Wm2, bm2, out);
}

// Round 2
// 843.157 us; speedup vs baseline: 1.1005x; 1.1005x over previous
//
#include <hip/hip_runtime.h>
#include <math.h>

#define D 128

// ---------------------------------------------------------------------------
// Collapsed linear GCN (unchanged math):
//   u0 = 1/N,  u_{k+1}[s] = sum_{e: src_e=s} inv_deg[dst_e] * u_k[dst_e]
//   mean(h3) = (((u3^T feat) W0 + s2 b0) W1 + s1 b1) W2 + b2
// R1: XCD-replicated scatter targets + workgroup-scope atomics so the
// atomic RMW executes in the XCD-local L2 instead of at the fabric
// coherence point (R0 evidence: 1 fabric write-req per atomic, 1/cy/XCD).
// ---------------------------------------------------------------------------

__device__ __forceinline__ int xcc_id() {
    int v;
    asm volatile("s_getreg_b32 %0, hwreg(HW_REG_XCC_ID)" : "=s"(v));
    return v & 7;
}

template<bool LOCAL>
__device__ __forceinline__ void fadd(float* p, float v) {
    if (LOCAL)
        __hip_atomic_fetch_add(p, v, __ATOMIC_RELAXED, __HIP_MEMORY_SCOPE_WORKGROUP);
    else
        atomicAdd(p, v);
}

// deg[dst] += 1 into this XCD's replica
template<bool LOCAL>
__global__ void deg_scatter(const int* __restrict__ dst_p, const int* __restrict__ dst_s,
                            float* __restrict__ rep, int E, int N) {
    float* base = rep;
    if (LOCAL) base += (size_t)xcc_id() * 2 * N;
    int i = blockIdx.x * blockDim.x + threadIdx.x;
    if (i < E) {
        fadd<LOCAL>(base + dst_p[i], 1.0f);
    } else {
        i -= E;
        if (i < E) fadd<LOCAL>(base + N + dst_s[i], 1.0f);
    }
}

// u_out[src] += w[dst] * scale into this XCD's replica (w covers 2N: p then s)
template<bool LOCAL>
__global__ void prop_scatter(const int* __restrict__ src_p, const int* __restrict__ dst_p,
                             const int* __restrict__ src_s, const int* __restrict__ dst_s,
                             const float* __restrict__ w, float* __restrict__ rep,
                             int E, int N, float scale) {
    float* base = rep;
    if (LOCAL) base += (size_t)xcc_id() * 2 * N;
    int i = blockIdx.x * blockDim.x + threadIdx.x;
    if (i < E) {
        fadd<LOCAL>(base + src_p[i], w[dst_p[i]] * scale);
    } else {
        i -= E;
        if (i < E) fadd<LOCAL>(base + N + src_s[i], w[N + dst_s[i]] * scale);
    }
}

// inv[i] = 1/max(sum_k rep[k][i], 1); zero reps
__global__ void reduce_inv(float* __restrict__ rep, float* __restrict__ inv, int N2, int K) {
    int i = blockIdx.x * blockDim.x + threadIdx.x;
    if (i >= N2) return;
    float s = 0.f;
    for (int k = 0; k < K; k++) {
        size_t idx = (size_t)k * N2 + i;
        s += rep[idx];
        rep[idx] = 0.f;
    }
    inv[i] = 1.0f / fmaxf(s, 1.0f);
}

// u[i] = sum_k rep[k][i]; optionally out_u, out_w = u*inv; optionally per-graph
// sums s_{s_idx+1} via one device atomic per block; optionally zero reps.
__global__ void reduce_u(float* __restrict__ rep, const float* __restrict__ inv,
                         float* __restrict__ out_u, float* __restrict__ out_w,
                         float* __restrict__ sums, int s_idx,
                         int N, int K, int zero) {
    const int N2 = 2 * N;
    int i = blockIdx.x * blockDim.x + threadIdx.x;
    float u = 0.f;
    if (i < N2) {
        for (int k = 0; k < K; k++) {
            size_t idx = (size_t)k * N2 + i;
            u += rep[idx];
            if (zero) rep[idx] = 0.f;
        }
        if (out_u) out_u[i] = u;
        if (out_w) out_w[i] = u * inv[i];
    }
    if (sums) {
        __shared__ float sm0[256], sm1[256];
        int in0 = (i < N) ? 1 : 0;
        int in1 = (i >= N && i < N2) ? 1 : 0;
        sm0[threadIdx.x] = in0 ? u : 0.f;
        sm1[threadIdx.x] = in1 ? u : 0.f;
        __syncthreads();
        for (int s = 128; s > 0; s >>= 1) {
            if ((int)threadIdx.x < s) {
                sm0[threadIdx.x] += sm0[threadIdx.x + s];
                sm1[threadIdx.x] += sm1[threadIdx.x + s];
            }
            __syncthreads();
        }
        if (threadIdx.x == 0) {
            if (sm0[0] != 0.f) atomicAdd(&sums[0 * 2 + s_idx], sm0[0]);
            if (sm1[0] != 0.f) atomicAdd(&sums[1 * 2 + s_idx], sm1[0]);
        }
    }
}

// r[g][c] = sum_n u3[g][n] * feat_g[n][c]
__global__ void featsum_kernel(const float* __restrict__ feat_p, const float* __restrict__ feat_s,
                               const float* __restrict__ u3, float* __restrict__ r, int N) {
    const int g = blockIdx.y;
    const float* feat = g ? feat_s : feat_p;
    const float* u = u3 + (size_t)g * N;
    const int nb = gridDim.x;
    const int col4 = threadIdx.x & 31;  // float4 column
    const int rgrp = threadIdx.x >> 5;  // 8 row groups
    const int rows_per_block = (N + nb - 1) / nb;
    const int r0 = blockIdx.x * rows_per_block;
    const int r1 = min(r0 + rows_per_block, N);

    const float4* f4 = (const float4*)feat;
    float4 acc = make_float4(0.f, 0.f, 0.f, 0.f);
    for (int n = r0 + rgrp; n < r1; n += 8) {
        float wv = u[n];
        float4 v = f4[(size_t)n * 32 + col4];
        acc.x += wv * v.x; acc.y += wv * v.y; acc.z += wv * v.z; acc.w += wv * v.w;
    }
    __shared__ float4 smem[256];
    smem[threadIdx.x] = acc;
    __syncthreads();
    if (rgrp == 0) {
        float4 t = smem[col4];
        for (int k = 1; k < 8; k++) {
            float4 o = smem[k * 32 + col4];
            t.x += o.x; t.y += o.y; t.z += o.z; t.w += o.w;
        }
        float* rr = r + (size_t)g * 128;
        atomicAdd(&rr[col4 * 4 + 0], t.x);
        atomicAdd(&rr[col4 * 4 + 1], t.y);
        atomicAdd(&rr[col4 * 4 + 2], t.z);
        atomicAdd(&rr[col4 * 4 + 3], t.w);
    }
}

// single block, 128 threads: dense chain + readout + match
__global__ void final_kernel(const float* __restrict__ r_base, const float* __restrict__ sums,
                             const float* __restrict__ W0, const float* __restrict__ b0,
                             const float* __restrict__ W1, const float* __restrict__ b1,
                             const float* __restrict__ W2, const float* __restrict__ b2,
                             const float* __restrict__ Wr, const float* __restrict__ br,
                             const float* __restrict__ Wm1, const float* __restrict__ bm1,
                             const float* __restrict__ Wm2, const float* __restrict__ bm2,
                             float* __restrict__ out) {
    __shared__ float t[128];
    __shared__ float c[256];
    const int j = threadIdx.x;  // 0..127

    for (int g = 0; g < 2; ++g) {
        const float s1 = sums[g * 2 + 0];
        const float s2 = sums[g * 2 + 1];
        t[j] = r_base[g * 128 + j];
        __syncthreads();
        float v = s2 * b0[j];
        for (int i = 0; i < 128; ++i) v += t[i] * W0[i * 128 + j];
        __syncthreads(); t[j] = v; __syncthreads();
        v = s1 * b1[j];
        for (int i = 0; i < 128; ++i) v += t[i] * W1[i * 128 + j];
        __syncthreads(); t[j] = v; __syncthreads();
        v = b2[j];
        for (int i = 0; i < 128; ++i) v += t[i] * W2[i * 128 + j];
        __syncthreads(); t[j] = v; __syncthreads();
        v = br[j];
        for (int i = 0; i < 128; ++i) v += t[i] * Wr[i * 128 + j];
        c[g * 128 + j] = 1.0f / (1.0f + expf(-v));
        __syncthreads();
    }

    float v = bm1[j];
    for (int i = 0; i < 256; ++i) v += c[i] * Wm1[i * 128 + j];
    t[j] = v * Wm2[j];
    __syncthreads();
    if (j == 0) {
        float d = bm2[0];
        for (int i = 0; i < 128; ++i) d += t[i];
        out[0] = 1.0f / (1.0f + expf(-d));
    }
}

extern "C" void kernel_launch(void* const* d_in, const int* in_sizes, int n_in,
                              void* d_out, int out_size, void* d_ws, size_t ws_size,
                              hipStream_t stream) {
    const float* feat_p = (const float*)d_in[0];
    const int*   src_p  = (const int*)d_in[1];
    const int*   dst_p  = (const int*)d_in[2];
    const float* feat_s = (const float*)d_in[3];
    const int*   src_s  = (const int*)d_in[4];
    const int*   dst_s  = (const int*)d_in[5];
    const float* W0 = (const float*)d_in[6];
    const float* b0 = (const float*)d_in[7];
    const float* W1 = (const float*)d_in[8];
    const float* b1 = (const float*)d_in[9];
    const float* W2 = (const float*)d_in[10];
    const float* b2 = (const float*)d_in[11];
    const float* Wr = (const float*)d_in[12];
    const float* br = (const float*)d_in[13];
    const float* Wm1 = (const float*)d_in[14];
    const float* bm1 = (const float*)d_in[15];
    const float* Wm2 = (const float*)d_in[16];
    const float* bm2 = (const float*)d_in[17];
    float* out = (float*)d_out;

    const int N = in_sizes[0] / D;   // 50000
    const int E = in_sizes[1];       // 1600000
    const int N2 = 2 * N;

    // ws layout (floats): rep[K][2N] | inv[2N] | u1[2N] | w1[2N] | w2[2N] | u3[2N] | r[256] | sums[4]
    const size_t need8 = ((size_t)8 * N2 + 5 * (size_t)N2 + 260) * sizeof(float);
    const int K = (ws_size >= need8) ? 8 : 1;
    const bool LOCAL = (K == 8);

    float* ws   = (float*)d_ws;
    float* rep  = ws;
    float* inv  = rep + (size_t)K * N2;
    float* u1   = inv + N2;
    float* w1   = u1 + N2;
    float* w2   = w1 + N2;
    float* u3   = w2 + N2;
    float* r    = u3 + N2;
    float* sums = r + 256;

    const size_t zero_bytes = ((size_t)K * N2 + 5 * (size_t)N2 + 260) * sizeof(float);
    hipMemsetAsync(d_ws, 0, zero_bytes, stream);

    const int BT = 256;
    const int gE2 = (2 * E + BT - 1) / BT;
    const int gN2 = (N2 + BT - 1) / BT;
    const float u0 = 1.0f / (float)N;

    if (LOCAL) {
        deg_scatter<true><<<gE2, BT, 0, stream>>>(dst_p, dst_s, rep, E, N);
        reduce_inv<<<gN2, BT, 0, stream>>>(rep, inv, N2, K);
        prop_scatter<true><<<gE2, BT, 0, stream>>>(src_p, dst_p, src_s, dst_s, inv, rep, E, N, u0);
        reduce_u<<<gN2, BT, 0, stream>>>(rep, inv, u1, w1, sums, 0, N, K, 1);
        prop_scatter<true><<<gE2, BT, 0, stream>>>(src_p, dst_p, src_s, dst_s, w1, rep, E, N, 1.0f);
        reduce_u<<<gN2, BT, 0, stream>>>(rep, inv, nullptr, w2, sums, 1, N, K, 1);
        prop_scatter<true><<<gE2, BT, 0, stream>>>(src_p, dst_p, src_s, dst_s, w2, rep, E, N, 1.0f);
        reduce_u<<<gN2, BT, 0, stream>>>(rep, inv, u3, nullptr, nullptr, 0, N, K, 0);
    } else {
        deg_scatter<false><<<gE2, BT, 0, stream>>>(dst_p, dst_s, rep, E, N);
        reduce_inv<<<gN2, BT, 0, stream>>>(rep, inv, N2, K);
        prop_scatter<false><<<gE2, BT, 0, stream>>>(src_p, dst_p, src_s, dst_s, inv, rep, E, N, u0);
        reduce_u<<<gN2, BT, 0, stream>>>(rep, inv, u1, w1, sums, 0, N, K, 1);
        prop_scatter<false><<<gE2, BT, 0, stream>>>(src_p, dst_p, src_s, dst_s, w1, rep, E, N, 1.0f);
        reduce_u<<<gN2, BT, 0, stream>>>(rep, inv, nullptr, w2, sums, 1, N, K, 1);
        prop_scatter<false><<<gE2, BT, 0, stream>>>(src_p, dst_p, src_s, dst_s, w2, rep, E, N, 1.0f);
        reduce_u<<<gN2, BT, 0, stream>>>(rep, inv, u3, nullptr, nullptr, 0, N, K, 0);
    }

    featsum_kernel<<<dim3(256, 2), BT, 0, stream>>>(feat_p, feat_s, u3, r, N);

    final_kernel<<<1, 128, 0, stream>>>(r, sums, W0, b0, W1, b1, W2, b2,
                                        Wr, br, Wm1, bm1, Wm2, bm2, out);
}

// Round 3
// 528.243 us; speedup vs baseline: 1.7566x; 1.5962x over previous
//
#include <hip/hip_runtime.h>
#include <math.h>

#define D 128

// ---------------------------------------------------------------------------
// Collapsed linear GCN (math unchanged, absmax 0.0 in R0/R1):
//   u0 = 1/N,  u_{k+1}[s] = sum_{e: src_e=s} inv_deg[dst_e] * u_k[dst_e]
//   mean(h3) = (((u3^T feat) W0 + s2 b0) W1 + s1 b1) W2 + b2
// R2: global fp32 atomics are pinned at ~1/cycle/XCD (R0/R1 evidence:
// WRITE_SIZE = #atomics x 32B, 20 G/s). Replace all scatter atomics with
// LDS-privatized histograms (ds_add_f32) + bulk flush + tree reduce.
// ---------------------------------------------------------------------------

// scatter pass: rep[g][h][b][HN] partial sums.
//   deg pass:  tgt = dst arrays, w = null  -> +1 per edge
//   prop pass: tgt = src arrays, oth = dst, w -> + w[g*N + dst[e]] * scale
__global__ void scan_scatter(const int* __restrict__ tgt_p, const int* __restrict__ oth_p,
                             const int* __restrict__ tgt_s, const int* __restrict__ oth_s,
                             const float* __restrict__ w, float* __restrict__ rep,
                             int E, int N, int HN, int B, int H, float scale) {
    const int b = blockIdx.x, h = blockIdx.y, g = blockIdx.z;
    const int* tgt = g ? tgt_s : tgt_p;
    const int* oth = g ? oth_s : oth_p;
    const float* wg = w ? (w + (size_t)g * N) : nullptr;

    extern __shared__ float lds[];  // HN floats
    for (int i = threadIdx.x; i < HN; i += blockDim.x) lds[i] = 0.f;
    __syncthreads();

    const int lo = h * HN;
    const int hi = min(lo + HN, N);
    int C = (E + B - 1) / B;
    C = (C + 3) & ~3;                       // chunk multiple of 4 for int4 loads
    const int e0 = b * C;
    const int e1 = min(e0 + C, E);

    for (int e = e0 + (int)threadIdx.x * 4; e < e1; e += blockDim.x * 4) {
        int4 t4 = *(const int4*)(tgt + e);  // e0, stride multiples of 4 -> aligned
        int ts[4] = {t4.x, t4.y, t4.z, t4.w};
        #pragma unroll
        for (int k = 0; k < 4; ++k) {
            int e2 = e + k;
            if (e2 < e1) {
                int t = ts[k];
                if (t >= lo && t < hi) {
                    float v = wg ? wg[oth[e2]] * scale : 1.0f;
                    atomicAdd(&lds[t - lo], v);
                }
            }
        }
    }
    __syncthreads();

    float* dst = rep + (((size_t)g * H + h) * B + b) * HN;
    if ((HN & 3) == 0) {
        float4* d4 = (float4*)dst;
        const float4* l4 = (const float4*)lds;
        for (int i = threadIdx.x; i < HN / 4; i += blockDim.x) d4[i] = l4[i];
    } else {
        for (int i = threadIdx.x; i < HN; i += blockDim.x) dst[i] = lds[i];
    }
}

// inv[i] = 1 / max(sum_b rep[...], 1)   over i in [0, 2N)
__global__ void reduce_inv(const float* __restrict__ rep, float* __restrict__ inv,
                           int N, int HN, int H, int B) {
    int i = blockIdx.x * blockDim.x + threadIdx.x;
    if (i >= 2 * N) return;
    int g = (i < N) ? 0 : 1;
    int n = i - g * N;
    int h = n / HN, l = n - h * HN;
    const float* base = rep + (((size_t)g * H + h) * B) * HN + l;
    float s = 0.f;
    for (int b = 0; b < B; b++) s += base[(size_t)b * HN];
    inv[i] = 1.0f / fmaxf(s, 1.0f);
}

// u[i] = sum_b rep[...]; optional out_u, out_w = u*inv; optional per-graph sums
__global__ void reduce_u(const float* __restrict__ rep, const float* __restrict__ inv,
                         float* __restrict__ out_u, float* __restrict__ out_w,
                         float* __restrict__ sums, int s_idx,
                         int N, int HN, int H, int B) {
    int i = blockIdx.x * blockDim.x + threadIdx.x;
    float u = 0.f;
    if (i < 2 * N) {
        int g = (i < N) ? 0 : 1;
        int n = i - g * N;
        int h = n / HN, l = n - h * HN;
        const float* base = rep + (((size_t)g * H + h) * B) * HN + l;
        for (int b = 0; b < B; b++) u += base[(size_t)b * HN];
        if (out_u) out_u[i] = u;
        if (out_w) out_w[i] = u * inv[i];
    }
    if (sums) {
        __shared__ float sm0[256], sm1[256];
        sm0[threadIdx.x] = (i < N) ? u : 0.f;
        sm1[threadIdx.x] = (i >= N && i < 2 * N) ? u : 0.f;
        __syncthreads();
        for (int s = 128; s > 0; s >>= 1) {
            if ((int)threadIdx.x < s) {
                sm0[threadIdx.x] += sm0[threadIdx.x + s];
                sm1[threadIdx.x] += sm1[threadIdx.x + s];
            }
            __syncthreads();
        }
        if (threadIdx.x == 0) {
            if (sm0[0] != 0.f) atomicAdd(&sums[0 * 2 + s_idx], sm0[0]);
            if (sm1[0] != 0.f) atomicAdd(&sums[1 * 2 + s_idx], sm1[0]);
        }
    }
}

// r[g][c] = sum_n u3[g*N+n] * feat_g[n][c]
__global__ void featsum_kernel(const float* __restrict__ feat_p, const float* __restrict__ feat_s,
                               const float* __restrict__ u3, float* __restrict__ r, int N) {
    const int g = blockIdx.y;
    const float* feat = g ? feat_s : feat_p;
    const float* u = u3 + (size_t)g * N;
    const int nb = gridDim.x;
    const int col4 = threadIdx.x & 31;
    const int rgrp = threadIdx.x >> 5;
    const int rows_per_block = (N + nb - 1) / nb;
    const int r0 = blockIdx.x * rows_per_block;
    const int r1 = min(r0 + rows_per_block, N);

    const float4* f4 = (const float4*)feat;
    float4 acc = make_float4(0.f, 0.f, 0.f, 0.f);
    for (int n = r0 + rgrp; n < r1; n += 8) {
        float wv = u[n];
        float4 v = f4[(size_t)n * 32 + col4];
        acc.x += wv * v.x; acc.y += wv * v.y; acc.z += wv * v.z; acc.w += wv * v.w;
    }
    __shared__ float4 smem[256];
    smem[threadIdx.x] = acc;
    __syncthreads();
    if (rgrp == 0) {
        float4 t = smem[col4];
        for (int k = 1; k < 8; k++) {
            float4 o = smem[k * 32 + col4];
            t.x += o.x; t.y += o.y; t.z += o.z; t.w += o.w;
        }
        float* rr = r + (size_t)g * 128;
        atomicAdd(&rr[col4 * 4 + 0], t.x);
        atomicAdd(&rr[col4 * 4 + 1], t.y);
        atomicAdd(&rr[col4 * 4 + 2], t.z);
        atomicAdd(&rr[col4 * 4 + 3], t.w);
    }
}

// single block, 128 threads: dense chain + readout + match
__global__ void final_kernel(const float* __restrict__ r_base, const float* __restrict__ sums,
                             const float* __restrict__ W0, const float* __restrict__ b0,
                             const float* __restrict__ W1, const float* __restrict__ b1,
                             const float* __restrict__ W2, const float* __restrict__ b2,
                             const float* __restrict__ Wr, const float* __restrict__ br,
                             const float* __restrict__ Wm1, const float* __restrict__ bm1,
                             const float* __restrict__ Wm2, const float* __restrict__ bm2,
                             float* __restrict__ out) {
    __shared__ float t[128];
    __shared__ float c[256];
    const int j = threadIdx.x;

    for (int g = 0; g < 2; ++g) {
        const float s1 = sums[g * 2 + 0];
        const float s2 = sums[g * 2 + 1];
        t[j] = r_base[g * 128 + j];
        __syncthreads();
        float v = s2 * b0[j];
        for (int i = 0; i < 128; ++i) v += t[i] * W0[i * 128 + j];
        __syncthreads(); t[j] = v; __syncthreads();
        v = s1 * b1[j];
        for (int i = 0; i < 128; ++i) v += t[i] * W1[i * 128 + j];
        __syncthreads(); t[j] = v; __syncthreads();
        v = b2[j];
        for (int i = 0; i < 128; ++i) v += t[i] * W2[i * 128 + j];
        __syncthreads(); t[j] = v; __syncthreads();
        v = br[j];
        for (int i = 0; i < 128; ++i) v += t[i] * Wr[i * 128 + j];
        c[g * 128 + j] = 1.0f / (1.0f + expf(-v));
        __syncthreads();
    }

    float v = bm1[j];
    for (int i = 0; i < 256; ++i) v += c[i] * Wm1[i * 128 + j];
    t[j] = v * Wm2[j];
    __syncthreads();
    if (j == 0) {
        float d = bm2[0];
        for (int i = 0; i < 128; ++i) d += t[i];
        out[0] = 1.0f / (1.0f + expf(-d));
    }
}

extern "C" void kernel_launch(void* const* d_in, const int* in_sizes, int n_in,
                              void* d_out, int out_size, void* d_ws, size_t ws_size,
                              hipStream_t stream) {
    const float* feat_p = (const float*)d_in[0];
    const int*   src_p  = (const int*)d_in[1];
    const int*   dst_p  = (const int*)d_in[2];
    const float* feat_s = (const float*)d_in[3];
    const int*   src_s  = (const int*)d_in[4];
    const int*   dst_s  = (const int*)d_in[5];
    const float* W0 = (const float*)d_in[6];
    const float* b0 = (const float*)d_in[7];
    const float* W1 = (const float*)d_in[8];
    const float* b1 = (const float*)d_in[9];
    const float* W2 = (const float*)d_in[10];
    const float* b2 = (const float*)d_in[11];
    const float* Wr = (const float*)d_in[12];
    const float* br = (const float*)d_in[13];
    const float* Wm1 = (const float*)d_in[14];
    const float* bm1 = (const float*)d_in[15];
    const float* Wm2 = (const float*)d_in[16];
    const float* bm2 = (const float*)d_in[17];
    float* out = (float*)d_out;

    const int N = in_sizes[0] / D;   // 50000
    const int E = in_sizes[1];       // 1600000
    const int N2 = 2 * N;

    const int H = 4;                          // node quarters
    int HN = (N + H - 1) / H;
    HN = (HN + 3) & ~3;                       // 12500 for N=50000; /4-able

    // ws layout (floats): r[256] | sums[4] | pad->272 | inv[2N] | w1[2N] | w2[2N] | u3[2N] | rep[2*H*B*HN]
    const size_t head = 272 + 4 * (size_t)N2;
    size_t avail = ws_size / sizeof(float);
    int B = 8;
    if (avail > head) {
        size_t bmax = (avail - head) / ((size_t)2 * H * HN);
        if (bmax > 32) bmax = 32;
        B = (int)(bmax & ~(size_t)7);         // multiple of 8 for XCD co-placement
        if (B < 1) B = 1;
    } else {
        B = 1;
    }

    float* ws   = (float*)d_ws;
    float* r    = ws;
    float* sums = ws + 256;
    float* inv  = ws + 272;
    float* w1   = inv + N2;
    float* w2   = w1 + N2;
    float* u3   = w2 + N2;
    float* rep  = u3 + N2;

    hipMemsetAsync(d_ws, 0, 272 * sizeof(float), stream);  // r + sums only

    const int BT = 256;
    const dim3 sgrid(B, H, 2);
    const size_t lds_bytes = (size_t)HN * sizeof(float);
    const int gN2 = (N2 + BT - 1) / BT;
    const float u0 = 1.0f / (float)N;

    // deg: scatter +1 on dst
    scan_scatter<<<sgrid, BT, lds_bytes, stream>>>(dst_p, nullptr, dst_s, nullptr,
                                                   nullptr, rep, E, N, HN, B, H, 1.0f);
    reduce_inv<<<gN2, BT, 0, stream>>>(rep, inv, N, HN, H, B);

    // prop1: u1[src] += inv[dst] * u0
    scan_scatter<<<sgrid, BT, lds_bytes, stream>>>(src_p, dst_p, src_s, dst_s,
                                                   inv, rep, E, N, HN, B, H, u0);
    reduce_u<<<gN2, BT, 0, stream>>>(rep, inv, nullptr, w1, sums, 0, N, HN, H, B);

    // prop2: u2[src] += w1[dst]
    scan_scatter<<<sgrid, BT, lds_bytes, stream>>>(src_p, dst_p, src_s, dst_s,
                                                   w1, rep, E, N, HN, B, H, 1.0f);
    reduce_u<<<gN2, BT, 0, stream>>>(rep, inv, nullptr, w2, sums, 1, N, HN, H, B);

    // prop3: u3[src] += w2[dst]
    scan_scatter<<<sgrid, BT, lds_bytes, stream>>>(src_p, dst_p, src_s, dst_s,
                                                   w2, rep, E, N, HN, B, H, 1.0f);
    reduce_u<<<gN2, BT, 0, stream>>>(rep, inv, u3, nullptr, nullptr, 0, N, HN, H, B);

    featsum_kernel<<<dim3(256, 2), BT, 0, stream>>>(feat_p, feat_s, u3, r, N);

    final_kernel<<<1, 128, 0, stream>>>(r, sums, W0, b0, W1, b1, W2, b2,
                                        Wr, br, Wm1, bm1, Wm2, bm2, out);
}

// Round 4
// 367.313 us; speedup vs baseline: 2.5262x; 1.4381x over previous
//
#include <hip/hip_runtime.h>
#include <math.h>

#define D 128

// ---------------------------------------------------------------------------
// Collapsed linear GCN (math unchanged, absmax 0.0 since R0):
//   u0 = 1/N,  u_{k+1}[s] = sum_{e: src_e=s} inv_deg[dst_e] * u_k[dst_e]
//   mean(h3) = (((u3^T feat) W0 + s2 b0) W1 + s1 b1) W2 + b2
// R2: LDS-privatized histograms killed the global-atomic fabric bottleneck.
// R3: scans were latency-bound (8% occupancy, 3% VALU). B=64 grid, int4 oth,
// 8-wide unroll with predicated gathers for ILP.
// ---------------------------------------------------------------------------

// scatter pass: rep[g][h][b][HN] partial sums.
//   deg pass:  tgt = dst arrays, w = null  -> +1 per edge
//   prop pass: tgt = src arrays, oth = dst, w -> + w[g*N + dst[e]] * scale
__global__ __launch_bounds__(256) void scan_scatter(
        const int* __restrict__ tgt_p, const int* __restrict__ oth_p,
        const int* __restrict__ tgt_s, const int* __restrict__ oth_s,
        const float* __restrict__ w, float* __restrict__ rep,
        int E, int N, int HN, int B, int H, float scale) {
    const int b = blockIdx.x, h = blockIdx.y, g = blockIdx.z;
    const int* tgt = g ? tgt_s : tgt_p;
    const int* oth = g ? oth_s : oth_p;
    const float* wg = w ? (w + (size_t)g * N) : nullptr;

    extern __shared__ float lds[];  // HN floats (HN % 4 == 0)
    {
        float4 z = make_float4(0.f, 0.f, 0.f, 0.f);
        float4* l4 = (float4*)lds;
        for (int i = threadIdx.x; i < HN / 4; i += blockDim.x) l4[i] = z;
    }
    __syncthreads();

    const int lo = h * HN;
    const int hi = min(lo + HN, N);
    const unsigned span = (unsigned)(hi - lo);
    int C = (E + B - 1) / B;
    C = (C + 7) & ~7;                       // chunk multiple of 8
    const int e0 = b * C;
    const int e1 = min(e0 + C, E);

    for (int e = e0 + (int)threadIdx.x * 8; e < e1; e += blockDim.x * 8) {
        if (e + 8 <= e1) {
            int4 ta = *(const int4*)(tgt + e);
            int4 tb = *(const int4*)(tgt + e + 4);
            int idx[8] = {ta.x, ta.y, ta.z, ta.w, tb.x, tb.y, tb.z, tb.w};
            bool hit[8];
            #pragma unroll
            for (int k = 0; k < 8; ++k) hit[k] = (unsigned)(idx[k] - lo) < span;
            if (wg) {
                int4 oa = *(const int4*)(oth + e);
                int4 ob = *(const int4*)(oth + e + 4);
                int od[8] = {oa.x, oa.y, oa.z, oa.w, ob.x, ob.y, ob.z, ob.w};
                float val[8];
                #pragma unroll
                for (int k = 0; k < 8; ++k) val[k] = hit[k] ? wg[od[k]] : 0.f;
                #pragma unroll
                for (int k = 0; k < 8; ++k)
                    if (hit[k]) atomicAdd(&lds[idx[k] - lo], val[k] * scale);
            } else {
                #pragma unroll
                for (int k = 0; k < 8; ++k)
                    if (hit[k]) atomicAdd(&lds[idx[k] - lo], 1.0f);
            }
        } else {
            for (int e2 = e; e2 < e1; ++e2) {
                int t = tgt[e2];
                if ((unsigned)(t - lo) < span) {
                    float v = wg ? wg[oth[e2]] * scale : 1.0f;
                    atomicAdd(&lds[t - lo], v);
                }
            }
        }
    }
    __syncthreads();

    float* dst = rep + (((size_t)g * H + h) * B + b) * HN;
    float4* d4 = (float4*)dst;
    const float4* l4 = (const float4*)lds;
    for (int i = threadIdx.x; i < HN / 4; i += blockDim.x) d4[i] = l4[i];
}

// inv[i] = 1 / max(sum_b rep[...], 1)   over i in [0, 2N)
__global__ void reduce_inv(const float* __restrict__ rep, float* __restrict__ inv,
                           int N, int HN, int H, int B) {
    int i = blockIdx.x * blockDim.x + threadIdx.x;
    if (i >= 2 * N) return;
    int g = (i < N) ? 0 : 1;
    int n = i - g * N;
    int h = n / HN, l = n - h * HN;
    const float* base = rep + (((size_t)g * H + h) * B) * HN + l;
    float s = 0.f;
    for (int b = 0; b < B; b++) s += base[(size_t)b * HN];
    inv[i] = 1.0f / fmaxf(s, 1.0f);
}

// u[i] = sum_b rep[...]; optional out_u, out_w = u*inv; optional per-graph sums
__global__ void reduce_u(const float* __restrict__ rep, const float* __restrict__ inv,
                         float* __restrict__ out_u, float* __restrict__ out_w,
                         float* __restrict__ sums, int s_idx,
                         int N, int HN, int H, int B) {
    int i = blockIdx.x * blockDim.x + threadIdx.x;
    float u = 0.f;
    if (i < 2 * N) {
        int g = (i < N) ? 0 : 1;
        int n = i - g * N;
        int h = n / HN, l = n - h * HN;
        const float* base = rep + (((size_t)g * H + h) * B) * HN + l;
        for (int b = 0; b < B; b++) u += base[(size_t)b * HN];
        if (out_u) out_u[i] = u;
        if (out_w) out_w[i] = u * inv[i];
    }
    if (sums) {
        __shared__ float sm0[256], sm1[256];
        sm0[threadIdx.x] = (i < N) ? u : 0.f;
        sm1[threadIdx.x] = (i >= N && i < 2 * N) ? u : 0.f;
        __syncthreads();
        for (int s = 128; s > 0; s >>= 1) {
            if ((int)threadIdx.x < s) {
                sm0[threadIdx.x] += sm0[threadIdx.x + s];
                sm1[threadIdx.x] += sm1[threadIdx.x + s];
            }
            __syncthreads();
        }
        if (threadIdx.x == 0) {
            if (sm0[0] != 0.f) atomicAdd(&sums[0 * 2 + s_idx], sm0[0]);
            if (sm1[0] != 0.f) atomicAdd(&sums[1 * 2 + s_idx], sm1[0]);
        }
    }
}

// r[g][c] = sum_n u3[g*N+n] * feat_g[n][c]
__global__ void featsum_kernel(const float* __restrict__ feat_p, const float* __restrict__ feat_s,
                               const float* __restrict__ u3, float* __restrict__ r, int N) {
    const int g = blockIdx.y;
    const float* feat = g ? feat_s : feat_p;
    const float* u = u3 + (size_t)g * N;
    const int nb = gridDim.x;
    const int col4 = threadIdx.x & 31;
    const int rgrp = threadIdx.x >> 5;
    const int rows_per_block = (N + nb - 1) / nb;
    const int r0 = blockIdx.x * rows_per_block;
    const int r1 = min(r0 + rows_per_block, N);

    const float4* f4 = (const float4*)feat;
    float4 acc = make_float4(0.f, 0.f, 0.f, 0.f);
    for (int n = r0 + rgrp; n < r1; n += 8) {
        float wv = u[n];
        float4 v = f4[(size_t)n * 32 + col4];
        acc.x += wv * v.x; acc.y += wv * v.y; acc.z += wv * v.z; acc.w += wv * v.w;
    }
    __shared__ float4 smem[256];
    smem[threadIdx.x] = acc;
    __syncthreads();
    if (rgrp == 0) {
        float4 t = smem[col4];
        for (int k = 1; k < 8; k++) {
            float4 o = smem[k * 32 + col4];
            t.x += o.x; t.y += o.y; t.z += o.z; t.w += o.w;
        }
        float* rr = r + (size_t)g * 128;
        atomicAdd(&rr[col4 * 4 + 0], t.x);
        atomicAdd(&rr[col4 * 4 + 1], t.y);
        atomicAdd(&rr[col4 * 4 + 2], t.z);
        atomicAdd(&rr[col4 * 4 + 3], t.w);
    }
}

// single block, 128 threads: dense chain + readout + match
__global__ void final_kernel(const float* __restrict__ r_base, const float* __restrict__ sums,
                             const float* __restrict__ W0, const float* __restrict__ b0,
                             const float* __restrict__ W1, const float* __restrict__ b1,
                             const float* __restrict__ W2, const float* __restrict__ b2,
                             const float* __restrict__ Wr, const float* __restrict__ br,
                             const float* __restrict__ Wm1, const float* __restrict__ bm1,
                             const float* __restrict__ Wm2, const float* __restrict__ bm2,
                             float* __restrict__ out) {
    __shared__ float t[128];
    __shared__ float c[256];
    const int j = threadIdx.x;

    for (int g = 0; g < 2; ++g) {
        const float s1 = sums[g * 2 + 0];
        const float s2 = sums[g * 2 + 1];
        t[j] = r_base[g * 128 + j];
        __syncthreads();
        float v = s2 * b0[j];
        for (int i = 0; i < 128; ++i) v += t[i] * W0[i * 128 + j];
        __syncthreads(); t[j] = v; __syncthreads();
        v = s1 * b1[j];
        for (int i = 0; i < 128; ++i) v += t[i] * W1[i * 128 + j];
        __syncthreads(); t[j] = v; __syncthreads();
        v = b2[j];
        for (int i = 0; i < 128; ++i) v += t[i] * W2[i * 128 + j];
        __syncthreads(); t[j] = v; __syncthreads();
        v = br[j];
        for (int i = 0; i < 128; ++i) v += t[i] * Wr[i * 128 + j];
        c[g * 128 + j] = 1.0f / (1.0f + expf(-v));
        __syncthreads();
    }

    float v = bm1[j];
    for (int i = 0; i < 256; ++i) v += c[i] * Wm1[i * 128 + j];
    t[j] = v * Wm2[j];
    __syncthreads();
    if (j == 0) {
        float d = bm2[0];
        for (int i = 0; i < 128; ++i) d += t[i];
        out[0] = 1.0f / (1.0f + expf(-d));
    }
}

extern "C" void kernel_launch(void* const* d_in, const int* in_sizes, int n_in,
                              void* d_out, int out_size, void* d_ws, size_t ws_size,
                              hipStream_t stream) {
    const float* feat_p = (const float*)d_in[0];
    const int*   src_p  = (const int*)d_in[1];
    const int*   dst_p  = (const int*)d_in[2];
    const float* feat_s = (const float*)d_in[3];
    const int*   src_s  = (const int*)d_in[4];
    const int*   dst_s  = (const int*)d_in[5];
    const float* W0 = (const float*)d_in[6];
    const float* b0 = (const float*)d_in[7];
    const float* W1 = (const float*)d_in[8];
    const float* b1 = (const float*)d_in[9];
    const float* W2 = (const float*)d_in[10];
    const float* b2 = (const float*)d_in[11];
    const float* Wr = (const float*)d_in[12];
    const float* br = (const float*)d_in[13];
    const float* Wm1 = (const float*)d_in[14];
    const float* bm1 = (const float*)d_in[15];
    const float* Wm2 = (const float*)d_in[16];
    const float* bm2 = (const float*)d_in[17];
    float* out = (float*)d_out;

    const int N = in_sizes[0] / D;   // 50000
    const int E = in_sizes[1];       // 1600000
    const int N2 = 2 * N;

    const int H = 4;                          // node quarters
    int HN = (N + H - 1) / H;
    HN = (HN + 3) & ~3;                       // 12500 for N=50000

    // ws layout (floats): r[256]|sums[4]|pad->272 | inv[2N]|w1[2N]|w2[2N]|u3[2N] | rep[2*H*B*HN]
    const size_t head = 272 + 4 * (size_t)N2;
    size_t avail = ws_size / sizeof(float);
    int B = 8;
    if (avail > head) {
        size_t bmax = (avail - head) / ((size_t)2 * H * HN);
        if (bmax > 64) bmax = 64;
        B = (int)(bmax & ~(size_t)7);         // multiple of 8
        if (B < 1) B = 1;
    } else {
        B = 1;
    }

    float* ws   = (float*)d_ws;
    float* r    = ws;
    float* sums = ws + 256;
    float* inv  = ws + 272;
    float* w1   = inv + N2;
    float* w2   = w1 + N2;
    float* u3   = w2 + N2;
    float* rep  = u3 + N2;

    hipMemsetAsync(d_ws, 0, 272 * sizeof(float), stream);  // r + sums only

    const int BT = 256;
    const dim3 sgrid(B, H, 2);
    const size_t lds_bytes = (size_t)HN * sizeof(float);
    const int gN2 = (N2 + BT - 1) / BT;
    const float u0 = 1.0f / (float)N;

    // deg: scatter +1 on dst
    scan_scatter<<<sgrid, BT, lds_bytes, stream>>>(dst_p, nullptr, dst_s, nullptr,
                                                   nullptr, rep, E, N, HN, B, H, 1.0f);
    reduce_inv<<<gN2, BT, 0, stream>>>(rep, inv, N, HN, H, B);

    // prop1: u1[src] += inv[dst] * u0
    scan_scatter<<<sgrid, BT, lds_bytes, stream>>>(src_p, dst_p, src_s, dst_s,
                                                   inv, rep, E, N, HN, B, H, u0);
    reduce_u<<<gN2, BT, 0, stream>>>(rep, inv, nullptr, w1, sums, 0, N, HN, H, B);

    // prop2: u2[src] += w1[dst]
    scan_scatter<<<sgrid, BT, lds_bytes, stream>>>(src_p, dst_p, src_s, dst_s,
                                                   w1, rep, E, N, HN, B, H, 1.0f);
    reduce_u<<<gN2, BT, 0, stream>>>(rep, inv, nullptr, w2, sums, 1, N, HN, H, B);

    // prop3: u3[src] += w2[dst]
    scan_scatter<<<sgrid, BT, lds_bytes, stream>>>(src_p, dst_p, src_s, dst_s,
                                                   w2, rep, E, N, HN, B, H, 1.0f);
    reduce_u<<<gN2, BT, 0, stream>>>(rep, inv, u3, nullptr, nullptr, 0, N, HN, H, B);

    featsum_kernel<<<dim3(256, 2), BT, 0, stream>>>(feat_p, feat_s, u3, r, N);

    final_kernel<<<1, 128, 0, stream>>>(r, sums, W0, b0, W1, b1, W2, b2,
                                        Wr, br, Wm1, bm1, Wm2, bm2, out);
}

// Round 5
// 334.505 us; speedup vs baseline: 2.7740x; 1.0981x over previous
//
#include <hip/hip_runtime.h>
#include <math.h>

#define D 128

// ---------------------------------------------------------------------------
// Collapsed linear GCN (math unchanged, absmax 0.0 since R0):
//   u0 = 1/N,  u_{k+1}[s] = sum_{e: src_e=s} inv_deg[dst_e] * u_k[dst_e]
//   mean(h3) = (((u3^T feat) W0 + s2 b0) W1 + s1 b1) W2 + b2
// R2: LDS-privatized histograms (no global atomics). R3: ILP + bigger grid.
// R4: ws is ~268 MB (poison fill evidence) -> B=96 (3 blocks/CU, LDS cap),
// 16-wide edge unroll, compile-unrolled reduces, featsum via block partials
// (atomic tail onto 8 cache lines was serializing at ~1 RMW/cy).
// ---------------------------------------------------------------------------

// scatter pass: rep[g][h][b][HN] partial sums.
//   deg pass:  tgt = dst arrays, w = null  -> +1 per edge
//   prop pass: tgt = src arrays, oth = dst, w -> + w[g*N + dst[e]] * scale
__global__ __launch_bounds__(256) void scan_scatter(
        const int* __restrict__ tgt_p, const int* __restrict__ oth_p,
        const int* __restrict__ tgt_s, const int* __restrict__ oth_s,
        const float* __restrict__ w, float* __restrict__ rep,
        int E, int N, int HN, int B, int H, float scale) {
    const int b = blockIdx.x, h = blockIdx.y, g = blockIdx.z;
    const int* tgt = g ? tgt_s : tgt_p;
    const int* oth = g ? oth_s : oth_p;
    const float* wg = w ? (w + (size_t)g * N) : nullptr;

    extern __shared__ float lds[];  // HN floats (HN % 4 == 0)
    {
        float4 z = make_float4(0.f, 0.f, 0.f, 0.f);
        float4* l4 = (float4*)lds;
        for (int i = threadIdx.x; i < HN / 4; i += blockDim.x) l4[i] = z;
    }
    __syncthreads();

    const int lo = h * HN;
    const int hi = min(lo + HN, N);
    const unsigned span = (unsigned)(hi - lo);
    int C = (E + B - 1) / B;
    C = (C + 15) & ~15;                     // chunk multiple of 16
    const int e0 = b * C;
    const int e1 = min(e0 + C, E);

    for (int e = e0 + (int)threadIdx.x * 16; e < e1; e += blockDim.x * 16) {
        if (e + 16 <= e1) {
            int idx[16];
            #pragma unroll
            for (int q = 0; q < 4; ++q) {
                int4 t4 = *(const int4*)(tgt + e + 4 * q);
                idx[4 * q + 0] = t4.x; idx[4 * q + 1] = t4.y;
                idx[4 * q + 2] = t4.z; idx[4 * q + 3] = t4.w;
            }
            bool hit[16];
            #pragma unroll
            for (int k = 0; k < 16; ++k) hit[k] = (unsigned)(idx[k] - lo) < span;
            if (wg) {
                int od[16];
                #pragma unroll
                for (int q = 0; q < 4; ++q) {
                    int4 o4 = *(const int4*)(oth + e + 4 * q);
                    od[4 * q + 0] = o4.x; od[4 * q + 1] = o4.y;
                    od[4 * q + 2] = o4.z; od[4 * q + 3] = o4.w;
                }
                float val[16];
                #pragma unroll
                for (int k = 0; k < 16; ++k) val[k] = hit[k] ? wg[od[k]] : 0.f;
                #pragma unroll
                for (int k = 0; k < 16; ++k)
                    if (hit[k]) atomicAdd(&lds[idx[k] - lo], val[k] * scale);
            } else {
                #pragma unroll
                for (int k = 0; k < 16; ++k)
                    if (hit[k]) atomicAdd(&lds[idx[k] - lo], 1.0f);
            }
        } else {
            for (int e2 = e; e2 < e1; ++e2) {
                int t = tgt[e2];
                if ((unsigned)(t - lo) < span) {
                    float v = wg ? wg[oth[e2]] * scale : 1.0f;
                    atomicAdd(&lds[t - lo], v);
                }
            }
        }
    }
    __syncthreads();

    float* dst = rep + (((size_t)g * H + h) * B + b) * HN;
    float4* d4 = (float4*)dst;
    const float4* l4 = (const float4*)lds;
    for (int i = threadIdx.x; i < HN / 4; i += blockDim.x) d4[i] = l4[i];
}

// inv[i] = 1 / max(sum_b rep[...], 1)   over i in [0, 2N)
__global__ void reduce_inv(const float* __restrict__ rep, float* __restrict__ inv,
                           int N, int HN, int H, int B) {
    int i = blockIdx.x * blockDim.x + threadIdx.x;
    if (i >= 2 * N) return;
    int g = (i < N) ? 0 : 1;
    int n = i - g * N;
    int h = n / HN, l = n - h * HN;
    const float* base = rep + (((size_t)g * H + h) * B) * HN + l;
    float s = 0.f;
    #pragma unroll 16
    for (int b = 0; b < B; b++) s += base[(size_t)b * HN];
    inv[i] = 1.0f / fmaxf(s, 1.0f);
}

// u[i] = sum_b rep[...]; optional out_u, out_w = u*inv; optional per-graph sums
__global__ void reduce_u(const float* __restrict__ rep, const float* __restrict__ inv,
                         float* __restrict__ out_u, float* __restrict__ out_w,
                         float* __restrict__ sums, int s_idx,
                         int N, int HN, int H, int B) {
    int i = blockIdx.x * blockDim.x + threadIdx.x;
    float u = 0.f;
    if (i < 2 * N) {
        int g = (i < N) ? 0 : 1;
        int n = i - g * N;
        int h = n / HN, l = n - h * HN;
        const float* base = rep + (((size_t)g * H + h) * B) * HN + l;
        #pragma unroll 16
        for (int b = 0; b < B; b++) u += base[(size_t)b * HN];
        if (out_u) out_u[i] = u;
        if (out_w) out_w[i] = u * inv[i];
    }
    if (sums) {
        __shared__ float sm0[256], sm1[256];
        sm0[threadIdx.x] = (i < N) ? u : 0.f;
        sm1[threadIdx.x] = (i >= N && i < 2 * N) ? u : 0.f;
        __syncthreads();
        for (int s = 128; s > 0; s >>= 1) {
            if ((int)threadIdx.x < s) {
                sm0[threadIdx.x] += sm0[threadIdx.x + s];
                sm1[threadIdx.x] += sm1[threadIdx.x + s];
            }
            __syncthreads();
        }
        if (threadIdx.x == 0) {
            if (sm0[0] != 0.f) atomicAdd(&sums[0 * 2 + s_idx], sm0[0]);
            if (sm1[0] != 0.f) atomicAdd(&sums[1 * 2 + s_idx], sm1[0]);
        }
    }
}

// fpart[(g*NB+blk)][c] = partial over this block's rows of u3[g*N+n]*feat_g[n][c]
__global__ __launch_bounds__(256) void featsum_kernel(
        const float* __restrict__ feat_p, const float* __restrict__ feat_s,
        const float* __restrict__ u3, float* __restrict__ fpart, int N) {
    const int g = blockIdx.y;
    const float* feat = g ? feat_s : feat_p;
    const float* u = u3 + (size_t)g * N;
    const int nb = gridDim.x;
    const int col4 = threadIdx.x & 31;
    const int rgrp = threadIdx.x >> 5;
    const int rows_per_block = (N + nb - 1) / nb;
    const int r0 = blockIdx.x * rows_per_block;
    const int r1 = min(r0 + rows_per_block, N);

    const float4* f4 = (const float4*)feat;
    float4 acc = make_float4(0.f, 0.f, 0.f, 0.f);
    for (int n = r0 + rgrp; n < r1; n += 8) {
        float wv = u[n];
        float4 v = f4[(size_t)n * 32 + col4];
        acc.x += wv * v.x; acc.y += wv * v.y; acc.z += wv * v.z; acc.w += wv * v.w;
    }
    __shared__ float4 smem[256];
    smem[threadIdx.x] = acc;
    __syncthreads();
    if (rgrp == 0) {
        float4 t = smem[col4];
        #pragma unroll
        for (int k = 1; k < 8; k++) {
            float4 o = smem[k * 32 + col4];
            t.x += o.x; t.y += o.y; t.z += o.z; t.w += o.w;
        }
        float4* dst = (float4*)(fpart + ((size_t)g * nb + blockIdx.x) * 128);
        dst[col4] = t;
    }
}

// single block, 128 threads: reduce fpart -> r, then dense chain + readout + match
__global__ void final_kernel(const float* __restrict__ fpart, int NB,
                             const float* __restrict__ sums,
                             const float* __restrict__ W0, const float* __restrict__ b0,
                             const float* __restrict__ W1, const float* __restrict__ b1,
                             const float* __restrict__ W2, const float* __restrict__ b2,
                             const float* __restrict__ Wr, const float* __restrict__ br,
                             const float* __restrict__ Wm1, const float* __restrict__ bm1,
                             const float* __restrict__ Wm2, const float* __restrict__ bm2,
                             float* __restrict__ out) {
    __shared__ float t[128];
    __shared__ float c[256];
    const int j = threadIdx.x;

    for (int g = 0; g < 2; ++g) {
        const float s1 = sums[g * 2 + 0];
        const float s2 = sums[g * 2 + 1];
        // r[g][j] = sum_b fpart[(g*NB+b)*128 + j]
        float rv = 0.f;
        const float* fp = fpart + (size_t)g * NB * 128 + j;
        #pragma unroll 16
        for (int b = 0; b < NB; ++b) rv += fp[(size_t)b * 128];
        t[j] = rv;
        __syncthreads();
        float v = s2 * b0[j];
        for (int i = 0; i < 128; ++i) v += t[i] * W0[i * 128 + j];
        __syncthreads(); t[j] = v; __syncthreads();
        v = s1 * b1[j];
        for (int i = 0; i < 128; ++i) v += t[i] * W1[i * 128 + j];
        __syncthreads(); t[j] = v; __syncthreads();
        v = b2[j];
        for (int i = 0; i < 128; ++i) v += t[i] * W2[i * 128 + j];
        __syncthreads(); t[j] = v; __syncthreads();
        v = br[j];
        for (int i = 0; i < 128; ++i) v += t[i] * Wr[i * 128 + j];
        c[g * 128 + j] = 1.0f / (1.0f + expf(-v));
        __syncthreads();
    }

    float v = bm1[j];
    for (int i = 0; i < 256; ++i) v += c[i] * Wm1[i * 128 + j];
    t[j] = v * Wm2[j];
    __syncthreads();
    if (j == 0) {
        float d = bm2[0];
        for (int i = 0; i < 128; ++i) d += t[i];
        out[0] = 1.0f / (1.0f + expf(-d));
    }
}

extern "C" void kernel_launch(void* const* d_in, const int* in_sizes, int n_in,
                              void* d_out, int out_size, void* d_ws, size_t ws_size,
                              hipStream_t stream) {
    const float* feat_p = (const float*)d_in[0];
    const int*   src_p  = (const int*)d_in[1];
    const int*   dst_p  = (const int*)d_in[2];
    const float* feat_s = (const float*)d_in[3];
    const int*   src_s  = (const int*)d_in[4];
    const int*   dst_s  = (const int*)d_in[5];
    const float* W0 = (const float*)d_in[6];
    const float* b0 = (const float*)d_in[7];
    const float* W1 = (const float*)d_in[8];
    const float* b1 = (const float*)d_in[9];
    const float* W2 = (const float*)d_in[10];
    const float* b2 = (const float*)d_in[11];
    const float* Wr = (const float*)d_in[12];
    const float* br = (const float*)d_in[13];
    const float* Wm1 = (const float*)d_in[14];
    const float* bm1 = (const float*)d_in[15];
    const float* Wm2 = (const float*)d_in[16];
    const float* bm2 = (const float*)d_in[17];
    float* out = (float*)d_out;

    const int N = in_sizes[0] / D;   // 50000
    const int E = in_sizes[1];       // 1600000
    const int N2 = 2 * N;

    const int H = 4;                          // node quarters
    int HN = (N + H - 1) / H;
    HN = (HN + 3) & ~3;                       // 12500 for N=50000
    const int NB = 384;                       // featsum blocks per graph

    // ws layout (floats):
    // sums[4]|pad->16 | inv[2N]|w1[2N]|w2[2N]|u3[2N] | fpart[2*NB*128] | rep[2*H*B*HN]
    const size_t head = 16 + 4 * (size_t)N2 + (size_t)2 * NB * 128;
    size_t avail = ws_size / sizeof(float);
    int B = 8;
    if (avail > head) {
        size_t bmax = (avail - head) / ((size_t)2 * H * HN);
        if (bmax > 96) bmax = 96;
        B = (int)(bmax & ~(size_t)7);         // multiple of 8
        if (B < 1) B = 1;
    } else {
        B = 1;
    }

    float* ws    = (float*)d_ws;
    float* sums  = ws;
    float* inv   = ws + 16;
    float* w1    = inv + N2;
    float* w2    = w1 + N2;
    float* u3    = w2 + N2;
    float* fpart = u3 + N2;
    float* rep   = fpart + (size_t)2 * NB * 128;

    hipMemsetAsync(d_ws, 0, 16 * sizeof(float), stream);  // sums only

    const int BT = 256;
    const dim3 sgrid(B, H, 2);
    const size_t lds_bytes = (size_t)HN * sizeof(float);
    const int gN2 = (N2 + BT - 1) / BT;
    const float u0 = 1.0f / (float)N;

    // deg: scatter +1 on dst
    scan_scatter<<<sgrid, BT, lds_bytes, stream>>>(dst_p, nullptr, dst_s, nullptr,
                                                   nullptr, rep, E, N, HN, B, H, 1.0f);
    reduce_inv<<<gN2, BT, 0, stream>>>(rep, inv, N, HN, H, B);

    // prop1: u1[src] += inv[dst] * u0
    scan_scatter<<<sgrid, BT, lds_bytes, stream>>>(src_p, dst_p, src_s, dst_s,
                                                   inv, rep, E, N, HN, B, H, u0);
    reduce_u<<<gN2, BT, 0, stream>>>(rep, inv, nullptr, w1, sums, 0, N, HN, H, B);

    // prop2: u2[src] += w1[dst]
    scan_scatter<<<sgrid, BT, lds_bytes, stream>>>(src_p, dst_p, src_s, dst_s,
                                                   w1, rep, E, N, HN, B, H, 1.0f);
    reduce_u<<<gN2, BT, 0, stream>>>(rep, inv, nullptr, w2, sums, 1, N, HN, H, B);

    // prop3: u3[src] += w2[dst]
    scan_scatter<<<sgrid, BT, lds_bytes, stream>>>(src_p, dst_p, src_s, dst_s,
                                                   w2, rep, E, N, HN, B, H, 1.0f);
    reduce_u<<<gN2, BT, 0, stream>>>(rep, inv, u3, nullptr, nullptr, 0, N, HN, H, B);

    featsum_kernel<<<dim3(NB, 2), BT, 0, stream>>>(feat_p, feat_s, u3, fpart, N);

    final_kernel<<<1, 128, 0, stream>>>(fpart, NB, sums, W0, b0, W1, b1, W2, b2,
                                        Wr, br, Wm1, bm1, Wm2, bm2, out);
}

// Round 6
// 311.605 us; speedup vs baseline: 2.9779x; 1.0735x over previous
//
#include <hip/hip_runtime.h>
#include <math.h>

#define D 128

// ---------------------------------------------------------------------------
// Collapsed linear GCN (math unchanged, absmax 0.0 since R0):
//   u0 = 1/N,  u_{k+1}[s] = sum_{e: src_e=s} inv_deg[dst_e] * u_k[dst_e]
//   mean(h3) = r@W0W1W2 + s2*(b0@W1W2) + s1*(b1@W2) + b2,  r = u3^T feat
// R2: LDS-privatized histograms. R3/R4: scan ILP + B=96 + featsum partials.
// R5: final_kernel was 54us latency-serial (1 block, dependent matvec chain)
// -> 512-thread split-K matvecs; reduces -> float4; featsum 4-row pipeline.
// ---------------------------------------------------------------------------

// scatter pass: rep[g][h][b][HN] partial sums.
__global__ __launch_bounds__(256) void scan_scatter(
        const int* __restrict__ tgt_p, const int* __restrict__ oth_p,
        const int* __restrict__ tgt_s, const int* __restrict__ oth_s,
        const float* __restrict__ w, float* __restrict__ rep,
        int E, int N, int HN, int B, int H, float scale) {
    const int b = blockIdx.x, h = blockIdx.y, g = blockIdx.z;
    const int* tgt = g ? tgt_s : tgt_p;
    const int* oth = g ? oth_s : oth_p;
    const float* wg = w ? (w + (size_t)g * N) : nullptr;

    extern __shared__ float lds[];  // HN floats (HN % 4 == 0)
    {
        float4 z = make_float4(0.f, 0.f, 0.f, 0.f);
        float4* l4 = (float4*)lds;
        for (int i = threadIdx.x; i < HN / 4; i += blockDim.x) l4[i] = z;
    }
    __syncthreads();

    const int lo = h * HN;
    const int hi = min(lo + HN, N);
    const unsigned span = (unsigned)(hi - lo);
    int C = (E + B - 1) / B;
    C = (C + 15) & ~15;
    const int e0 = b * C;
    const int e1 = min(e0 + C, E);

    for (int e = e0 + (int)threadIdx.x * 16; e < e1; e += blockDim.x * 16) {
        if (e + 16 <= e1) {
            int idx[16];
            #pragma unroll
            for (int q = 0; q < 4; ++q) {
                int4 t4 = *(const int4*)(tgt + e + 4 * q);
                idx[4 * q + 0] = t4.x; idx[4 * q + 1] = t4.y;
                idx[4 * q + 2] = t4.z; idx[4 * q + 3] = t4.w;
            }
            bool hit[16];
            #pragma unroll
            for (int k = 0; k < 16; ++k) hit[k] = (unsigned)(idx[k] - lo) < span;
            if (wg) {
                int od[16];
                #pragma unroll
                for (int q = 0; q < 4; ++q) {
                    int4 o4 = *(const int4*)(oth + e + 4 * q);
                    od[4 * q + 0] = o4.x; od[4 * q + 1] = o4.y;
                    od[4 * q + 2] = o4.z; od[4 * q + 3] = o4.w;
                }
                float val[16];
                #pragma unroll
                for (int k = 0; k < 16; ++k) val[k] = hit[k] ? wg[od[k]] : 0.f;
                #pragma unroll
                for (int k = 0; k < 16; ++k)
                    if (hit[k]) atomicAdd(&lds[idx[k] - lo], val[k] * scale);
            } else {
                #pragma unroll
                for (int k = 0; k < 16; ++k)
                    if (hit[k]) atomicAdd(&lds[idx[k] - lo], 1.0f);
            }
        } else {
            for (int e2 = e; e2 < e1; ++e2) {
                int t = tgt[e2];
                if ((unsigned)(t - lo) < span) {
                    float v = wg ? wg[oth[e2]] * scale : 1.0f;
                    atomicAdd(&lds[t - lo], v);
                }
            }
        }
    }
    __syncthreads();

    float* dst = rep + (((size_t)g * H + h) * B + b) * HN;
    float4* d4 = (float4*)dst;
    const float4* l4 = (const float4*)lds;
    for (int i = threadIdx.x; i < HN / 4; i += blockDim.x) d4[i] = l4[i];
}

// inv[i] = 1 / max(sum_b rep[...], 1), float4 per thread (N, HN mult of 4)
__global__ void reduce_inv(const float* __restrict__ rep, float* __restrict__ inv,
                           int N, int HN, int H, int B) {
    int i = (blockIdx.x * blockDim.x + threadIdx.x) * 4;
    if (i >= 2 * N) return;
    int g = (i < N) ? 0 : 1;
    int n = i - g * N;
    int h = n / HN, l = n - h * HN;
    const float* base = rep + (((size_t)g * H + h) * B) * HN + l;
    float4 s = make_float4(0.f, 0.f, 0.f, 0.f);
    #pragma unroll 16
    for (int b = 0; b < B; b++) {
        float4 v = *(const float4*)(base + (size_t)b * HN);
        s.x += v.x; s.y += v.y; s.z += v.z; s.w += v.w;
    }
    float4 r;
    r.x = 1.0f / fmaxf(s.x, 1.0f); r.y = 1.0f / fmaxf(s.y, 1.0f);
    r.z = 1.0f / fmaxf(s.z, 1.0f); r.w = 1.0f / fmaxf(s.w, 1.0f);
    *(float4*)(inv + i) = r;
}

// u = sum_b rep; optional out_u, out_w = u*inv; optional per-graph sums
__global__ void reduce_u(const float* __restrict__ rep, const float* __restrict__ inv,
                         float* __restrict__ out_u, float* __restrict__ out_w,
                         float* __restrict__ sums, int s_idx,
                         int N, int HN, int H, int B) {
    int i = (blockIdx.x * blockDim.x + threadIdx.x) * 4;
    float tp = 0.f, ts = 0.f;
    if (i < 2 * N) {
        int g = (i < N) ? 0 : 1;
        int n = i - g * N;
        int h = n / HN, l = n - h * HN;
        const float* base = rep + (((size_t)g * H + h) * B) * HN + l;
        float4 u = make_float4(0.f, 0.f, 0.f, 0.f);
        #pragma unroll 16
        for (int b = 0; b < B; b++) {
            float4 v = *(const float4*)(base + (size_t)b * HN);
            u.x += v.x; u.y += v.y; u.z += v.z; u.w += v.w;
        }
        if (out_u) *(float4*)(out_u + i) = u;
        if (out_w) {
            float4 iv = *(const float4*)(inv + i);
            float4 wv = make_float4(u.x * iv.x, u.y * iv.y, u.z * iv.z, u.w * iv.w);
            *(float4*)(out_w + i) = wv;
        }
        float t = u.x + u.y + u.z + u.w;
        if (g == 0) tp = t; else ts = t;
    }
    if (sums) {
        __shared__ float sm0[256], sm1[256];
        sm0[threadIdx.x] = tp;
        sm1[threadIdx.x] = ts;
        __syncthreads();
        for (int s = 128; s > 0; s >>= 1) {
            if ((int)threadIdx.x < s) {
                sm0[threadIdx.x] += sm0[threadIdx.x + s];
                sm1[threadIdx.x] += sm1[threadIdx.x + s];
            }
            __syncthreads();
        }
        if (threadIdx.x == 0) {
            if (sm0[0] != 0.f) atomicAdd(&sums[0 * 2 + s_idx], sm0[0]);
            if (sm1[0] != 0.f) atomicAdd(&sums[1 * 2 + s_idx], sm1[0]);
        }
    }
}

// fpart[(g*NB+blk)][c] = partial over this block's rows of u3[g*N+n]*feat_g[n][c]
__global__ __launch_bounds__(256) void featsum_kernel(
        const float* __restrict__ feat_p, const float* __restrict__ feat_s,
        const float* __restrict__ u3, float* __restrict__ fpart, int N) {
    const int g = blockIdx.y;
    const float* feat = g ? feat_s : feat_p;
    const float* u = u3 + (size_t)g * N;
    const int nb = gridDim.x;
    const int col4 = threadIdx.x & 31;
    const int rgrp = threadIdx.x >> 5;  // 0..7
    const int rows_per_block = (N + nb - 1) / nb;
    const int r0 = blockIdx.x * rows_per_block;
    const int r1 = min(r0 + rows_per_block, N);

    const float4* f4 = (const float4*)feat;
    float4 acc = make_float4(0.f, 0.f, 0.f, 0.f);
    int n = r0 + rgrp;
    for (; n + 24 < r1; n += 32) {
        float w0 = u[n], w1 = u[n + 8], w2 = u[n + 16], w3 = u[n + 24];
        float4 v0 = f4[(size_t)n * 32 + col4];
        float4 v1 = f4[(size_t)(n + 8) * 32 + col4];
        float4 v2 = f4[(size_t)(n + 16) * 32 + col4];
        float4 v3 = f4[(size_t)(n + 24) * 32 + col4];
        acc.x += w0 * v0.x + w1 * v1.x + w2 * v2.x + w3 * v3.x;
        acc.y += w0 * v0.y + w1 * v1.y + w2 * v2.y + w3 * v3.y;
        acc.z += w0 * v0.z + w1 * v1.z + w2 * v2.z + w3 * v3.z;
        acc.w += w0 * v0.w + w1 * v1.w + w2 * v2.w + w3 * v3.w;
    }
    for (; n < r1; n += 8) {
        float wv = u[n];
        float4 v = f4[(size_t)n * 32 + col4];
        acc.x += wv * v.x; acc.y += wv * v.y; acc.z += wv * v.z; acc.w += wv * v.w;
    }
    __shared__ float4 smem[256];
    smem[threadIdx.x] = acc;
    __syncthreads();
    if (rgrp == 0) {
        float4 t = smem[col4];
        #pragma unroll
        for (int k = 1; k < 8; k++) {
            float4 o = smem[k * 32 + col4];
            t.x += o.x; t.y += o.y; t.z += o.z; t.w += o.w;
        }
        float4* dst = (float4*)(fpart + ((size_t)g * nb + blockIdx.x) * 128);
        dst[col4] = t;
    }
}

// 512 threads: split-K matvecs. j = tid&127 (output col), h = tid>>7 (K-slice).
__global__ __launch_bounds__(512) void final_kernel(
        const float* __restrict__ fpart, int NB,
        const float* __restrict__ sums,
        const float* __restrict__ W0, const float* __restrict__ b0,
        const float* __restrict__ W1, const float* __restrict__ b1,
        const float* __restrict__ W2, const float* __restrict__ b2,
        const float* __restrict__ Wr, const float* __restrict__ br,
        const float* __restrict__ Wm1, const float* __restrict__ bm1,
        const float* __restrict__ Wm2, const float* __restrict__ bm2,
        float* __restrict__ out) {
    __shared__ float x[128];
    __shared__ float part[4][128];
    __shared__ float rvec[256];
    __shared__ float Avec[128], Bvec[128];
    __shared__ float gv[256];
    const int tid = threadIdx.x;
    const int j = tid & 127;
    const int h = tid >> 7;   // 0..3

    // split-K matvec: buf <- buf @ W  (buf 128 in LDS, W 128x128 row-major)
    auto mv128 = [&](const float* __restrict__ W, float* __restrict__ buf) {
        float p = 0.f;
        const float* Wp = W + (size_t)(h * 32) * 128 + j;
        #pragma unroll
        for (int i = 0; i < 32; ++i) p += buf[h * 32 + i] * Wp[(size_t)i * 128];
        part[h][j] = p;
        __syncthreads();
        if (h == 0) buf[j] = part[0][j] + part[1][j] + part[2][j] + part[3][j];
        __syncthreads();
    };

    // 1. fpart reduce -> rvec  (NB % 4 == 0)
    const int nb4 = NB / 4;
    for (int g = 0; g < 2; ++g) {
        const float* fp = fpart + (size_t)(g * NB + h * nb4) * 128 + j;
        float p = 0.f;
        #pragma unroll 16
        for (int b = 0; b < nb4; ++b) p += fp[(size_t)b * 128];
        part[h][j] = p;
        __syncthreads();
        if (h == 0) rvec[g * 128 + j] = part[0][j] + part[1][j] + part[2][j] + part[3][j];
        __syncthreads();
    }

    // 2. bias chains: Avec = b0@W1@W2 (coeff s2), Bvec = b1@W2 (coeff s1)
    if (tid < 128) x[tid] = b0[tid];
    __syncthreads();
    mv128(W1, x);
    mv128(W2, x);
    if (tid < 128) Avec[tid] = x[tid];
    __syncthreads();
    if (tid < 128) x[tid] = b1[tid];
    __syncthreads();
    mv128(W2, x);
    if (tid < 128) Bvec[tid] = x[tid];
    __syncthreads();

    // 3. per-graph: mean(h3) = r@W0W1W2 + s2*Avec + s1*Bvec + b2; g = sig(.@Wr+br)
    for (int g = 0; g < 2; ++g) {
        const float s1 = sums[g * 2 + 0];
        const float s2 = sums[g * 2 + 1];
        if (tid < 128) x[tid] = rvec[g * 128 + tid];
        __syncthreads();
        mv128(W0, x);
        mv128(W1, x);
        mv128(W2, x);
        if (tid < 128) x[tid] += s2 * Avec[tid] + s1 * Bvec[tid] + b2[tid];
        __syncthreads();
        mv128(Wr, x);
        if (tid < 128) gv[g * 128 + tid] = 1.0f / (1.0f + expf(-(x[tid] + br[tid])));
        __syncthreads();
    }

    // 4. match: y = gv@Wm1 + bm1; d = y.Wm2 + bm2; out = sigmoid(d)
    {
        float p = 0.f;
        const float* Wp = Wm1 + (size_t)(h * 64) * 128 + j;
        #pragma unroll
        for (int i = 0; i < 64; ++i) p += gv[h * 64 + i] * Wp[(size_t)i * 128];
        part[h][j] = p;
        __syncthreads();
        if (h == 0)
            part[0][j] = (part[0][j] + part[1][j] + part[2][j] + part[3][j] + bm1[j]) * Wm2[j];
        __syncthreads();
        if (tid < 64) part[0][tid] += part[0][tid + 64];
        __syncthreads();
        if (tid < 32) part[0][tid] += part[0][tid + 32];
        __syncthreads();
        if (tid < 16) part[0][tid] += part[0][tid + 16];
        __syncthreads();
        if (tid < 8) part[0][tid] += part[0][tid + 8];
        __syncthreads();
        if (tid < 4) part[0][tid] += part[0][tid + 4];
        __syncthreads();
        if (tid < 2) part[0][tid] += part[0][tid + 2];
        __syncthreads();
        if (tid == 0) out[0] = 1.0f / (1.0f + expf(-(part[0][0] + part[0][1] + bm2[0])));
    }
}

extern "C" void kernel_launch(void* const* d_in, const int* in_sizes, int n_in,
                              void* d_out, int out_size, void* d_ws, size_t ws_size,
                              hipStream_t stream) {
    const float* feat_p = (const float*)d_in[0];
    const int*   src_p  = (const int*)d_in[1];
    const int*   dst_p  = (const int*)d_in[2];
    const float* feat_s = (const float*)d_in[3];
    const int*   src_s  = (const int*)d_in[4];
    const int*   dst_s  = (const int*)d_in[5];
    const float* W0 = (const float*)d_in[6];
    const float* b0 = (const float*)d_in[7];
    const float* W1 = (const float*)d_in[8];
    const float* b1 = (const float*)d_in[9];
    const float* W2 = (const float*)d_in[10];
    const float* b2 = (const float*)d_in[11];
    const float* Wr = (const float*)d_in[12];
    const float* br = (const float*)d_in[13];
    const float* Wm1 = (const float*)d_in[14];
    const float* bm1 = (const float*)d_in[15];
    const float* Wm2 = (const float*)d_in[16];
    const float* bm2 = (const float*)d_in[17];
    float* out = (float*)d_out;

    const int N = in_sizes[0] / D;   // 50000
    const int E = in_sizes[1];       // 1600000
    const int N2 = 2 * N;

    const int H = 4;
    int HN = (N + H - 1) / H;
    HN = (HN + 3) & ~3;              // 12500
    const int NB = 768;              // featsum blocks per graph (mult of 4)

    // ws (floats): sums[4]|pad16 | inv[2N]|w1[2N]|w2[2N]|u3[2N] | fpart[2*NB*128] | rep
    const size_t head = 16 + 4 * (size_t)N2 + (size_t)2 * NB * 128;
    size_t avail = ws_size / sizeof(float);
    int B = 8;
    if (avail > head) {
        size_t bmax = (avail - head) / ((size_t)2 * H * HN);
        if (bmax > 96) bmax = 96;
        B = (int)(bmax & ~(size_t)7);
        if (B < 1) B = 1;
    } else {
        B = 1;
    }

    float* ws    = (float*)d_ws;
    float* sums  = ws;
    float* inv   = ws + 16;
    float* w1    = inv + N2;
    float* w2    = w1 + N2;
    float* u3    = w2 + N2;
    float* fpart = u3 + N2;
    float* rep   = fpart + (size_t)2 * NB * 128;

    hipMemsetAsync(d_ws, 0, 16 * sizeof(float), stream);  // sums only

    const int BT = 256;
    const dim3 sgrid(B, H, 2);
    const size_t lds_bytes = (size_t)HN * sizeof(float);
    const int gQ = (N2 / 4 + BT - 1) / BT;
    const float u0 = 1.0f / (float)N;

    scan_scatter<<<sgrid, BT, lds_bytes, stream>>>(dst_p, nullptr, dst_s, nullptr,
                                                   nullptr, rep, E, N, HN, B, H, 1.0f);
    reduce_inv<<<gQ, BT, 0, stream>>>(rep, inv, N, HN, H, B);

    scan_scatter<<<sgrid, BT, lds_bytes, stream>>>(src_p, dst_p, src_s, dst_s,
                                                   inv, rep, E, N, HN, B, H, u0);
    reduce_u<<<gQ, BT, 0, stream>>>(rep, inv, nullptr, w1, sums, 0, N, HN, H, B);

    scan_scatter<<<sgrid, BT, lds_bytes, stream>>>(src_p, dst_p, src_s, dst_s,
                                                   w1, rep, E, N, HN, B, H, 1.0f);
    reduce_u<<<gQ, BT, 0, stream>>>(rep, inv, nullptr, w2, sums, 1, N, HN, H, B);

    scan_scatter<<<sgrid, BT, lds_bytes, stream>>>(src_p, dst_p, src_s, dst_s,
                                                   w2, rep, E, N, HN, B, H, 1.0f);
    reduce_u<<<gQ, BT, 0, stream>>>(rep, inv, u3, nullptr, nullptr, 0, N, HN, H, B);

    featsum_kernel<<<dim3(NB, 2), BT, 0, stream>>>(feat_p, feat_s, u3, fpart, N);

    final_kernel<<<1, 512, 0, stream>>>(fpart, NB, sums, W0, b0, W1, b1, W2, b2,
                                        Wr, br, Wm1, bm1, Wm2, bm2, out);
}